// Round 5
// baseline (152.754 us; speedup 1.0000x reference)
//
#include <hip/hip_runtime.h>
#include <stdint.h>

#define MD 4096
#define ND 4096
#define KD 4096
#define BK 64
#define NT (KD / BK)   // 64 K-tiles

typedef __bf16 bf16x8 __attribute__((ext_vector_type(8)));
typedef float f32x4 __attribute__((ext_vector_type(4)));

__device__ __forceinline__ uint32_t f32_to_bf16(float f) {
    union { float f; uint32_t u; } v; v.f = f;
    return (v.u + 0x7FFFu + ((v.u >> 16) & 1u)) >> 16;
}

#define GLDS16(gp, lp) \
    __builtin_amdgcn_global_load_lds((const __attribute__((address_space(1))) void*)(gp), \
                                     (__attribute__((address_space(3))) void*)(lp), 16, 0, 0)

// ---------------------------------------------------------------------------
// Fused prelude: blocks [0,4096) dequant W_q (int32-widened packed bytes) to
// bf16 Wb[4096][4096]; blocks [4096,12288) convert x fp32->bf16.
// W row o<2048: high nibbles of Wq[o*4096+i]; row o>=2048: low nibbles.
// group g = o*64 + i/64.
// ---------------------------------------------------------------------------
__global__ void prep_kernel(const int* __restrict__ Wq,
                            const float* __restrict__ scale,
                            const float* __restrict__ zero,
                            const float* __restrict__ x,
                            uint16_t* __restrict__ Wb,
                            uint16_t* __restrict__ xb) {
    int blk = blockIdx.x;
    if (blk < 4096) {
        int t = blk * 256 + threadIdx.x;             // 1048576 threads
        int o  = t >> 9;
        int i0 = (t & 511) << 3;
        const uint4* wp = (const uint4*)Wq;
        uint4 pa = wp[t * 2], pb = wp[t * 2 + 1];
        uint32_t v[8] = {pa.x, pa.y, pa.z, pa.w, pb.x, pb.y, pb.z, pb.w};
        int gh = (o << 6) + (i0 >> 6);
        int gl = gh + (2048 << 6);
        float sh = scale[gh], zh = zero[gh];
        float sl = scale[gl], zl = zero[gl];
        uint32_t hw[4], lw[4];
#pragma unroll
        for (int p = 0; p < 4; ++p) {
            uint32_t b0 = v[p * 2], b1 = v[p * 2 + 1];
            uint32_t h0 = f32_to_bf16(((float)((b0 >> 4) & 15u) - zh) * sh);
            uint32_t h1 = f32_to_bf16(((float)((b1 >> 4) & 15u) - zh) * sh);
            uint32_t l0 = f32_to_bf16(((float)(b0 & 15u) - zl) * sl);
            uint32_t l1 = f32_to_bf16(((float)(b1 & 15u) - zl) * sl);
            hw[p] = h0 | (h1 << 16);
            lw[p] = l0 | (l1 << 16);
        }
        uint4 hv = {hw[0], hw[1], hw[2], hw[3]};
        uint4 lv = {lw[0], lw[1], lw[2], lw[3]};
        *(uint4*)&Wb[(size_t)o * KD + i0]          = hv;
        *(uint4*)&Wb[(size_t)(o + 2048) * KD + i0] = lv;
    } else {
        int t = (blk - 4096) * 256 + threadIdx.x;    // 2097152 threads
        const float4* xp = (const float4*)x;
        float4 a = xp[t * 2], b = xp[t * 2 + 1];
        uint4 o;
        o.x = f32_to_bf16(a.x) | (f32_to_bf16(a.y) << 16);
        o.y = f32_to_bf16(a.z) | (f32_to_bf16(a.w) << 16);
        o.z = f32_to_bf16(b.x) | (f32_to_bf16(b.y) << 16);
        o.w = f32_to_bf16(b.z) | (f32_to_bf16(b.w) << 16);
        ((uint4*)xb)[t] = o;
    }
}

// ---------------------------------------------------------------------------
// 256x256 tile, BK=64, 8 waves (2Mx4N, each 128x64).
// ONE sync point per K-tile: issue all 8 stage loads (tile t+1 -> buf q)
// immediately after the barrier that closed tile t-1 (proving q free), run
// 4 MFMA clusters (24 ds_read_b128, 64 MFMA) barrier-free, then VM(0);BAR.
// By the VM(0) the stages are ~4 phases (>2000 cyc) old >> HBM latency, so
// the wait is ~free. Within-tile wave drift touches only disjoint buffers.
// LDS region(buf,mat,kh) = 256 rows x 32 cols bf16 (16 KiB); 8 regions=128 KiB.
// ---------------------------------------------------------------------------
#define BAR()  asm volatile("s_barrier" ::: "memory")
#define LGKM0() do { asm volatile("s_waitcnt lgkmcnt(0)" ::: "memory"); \
                     __builtin_amdgcn_sched_barrier(0); } while (0)
#define VM(N)  asm volatile("s_waitcnt vmcnt(" #N ")" ::: "memory")

#define STAGE(PTR, GROW0, BUF, MAT, KH, KBASE) do {                                   \
    const uint16_t* _g = (PTR) + (size_t)((GROW0) + (tid >> 2)) * KD                  \
                         + (KBASE) + (KH) * 32 + sslot * 8;                           \
    uint16_t* _d = lds + (((BUF) * 2 + (MAT)) * 2 + (KH)) * 8192 + wave * 512;        \
    GLDS16(_g, _d);                                                                   \
    GLDS16(_g + 128 * KD, _d + 4096);                                                 \
} while (0)

#define LOADA(P, KH, CH) do {                                                         \
    const uint16_t* _Ar = lds + (((P) * 2 + 0) * 2 + (KH)) * 8192;                    \
    _Pragma("unroll")                                                                 \
    for (int m = 0; m < 4; ++m)                                                       \
        a[m] = *(const bf16x8*)&_Ar[(wr * 128 + ((CH) * 4 + m) * 16 + lr) * 32 + sx * 8]; \
} while (0)

#define LOADB(P, KH) do {                                                             \
    const uint16_t* _Br = lds + (((P) * 2 + 1) * 2 + (KH)) * 8192;                    \
    _Pragma("unroll")                                                                 \
    for (int n = 0; n < 4; ++n)                                                       \
        b[n] = *(const bf16x8*)&_Br[(wc * 64 + n * 16 + lr) * 32 + sx * 8];           \
} while (0)

#define MFMAQ(CH) do {                                                                \
    __builtin_amdgcn_s_setprio(1);                                                    \
    _Pragma("unroll")                                                                 \
    for (int m = 0; m < 4; ++m)                                                       \
    _Pragma("unroll")                                                                 \
    for (int n = 0; n < 4; ++n)                                                       \
        acc[(CH) * 4 + m][n] = __builtin_amdgcn_mfma_f32_16x16x32_bf16(               \
            a[m], b[n], acc[(CH) * 4 + m][n], 0, 0, 0);                               \
    __builtin_amdgcn_s_setprio(0);                                                    \
} while (0)

__global__ __launch_bounds__(512, 2)
void gemm_kernel(const uint16_t* __restrict__ A,
                 const uint16_t* __restrict__ B,
                 float* __restrict__ C) {
    __shared__ uint16_t lds[65536];   // 128 KiB

    const int tid  = threadIdx.x;
    const int wave = tid >> 6;
    const int lane = tid & 63;
    const int wr = wave >> 2;                  // 0..1
    const int wc = wave & 3;                   // 0..3
    const int lr = lane & 15;
    const int ls = lane >> 4;
    const int sx = ls ^ ((lr >> 1) & 3);              // swizzled read slot
    const int sslot = (tid & 3) ^ ((tid >> 3) & 3);   // pre-swizzled stage source slot

    // XCD-aware swizzle: 256 wgs, 8 XCDs, 32 contiguous tiles per XCD
    int bid = blockIdx.x;
    int wg = (bid & 7) * 32 + (bid >> 3);
    const int bm0 = (wg >> 4) * 256;
    const int bn0 = (wg & 15) * 256;

    f32x4 acc[8][4];
#pragma unroll
    for (int m = 0; m < 8; ++m)
#pragma unroll
        for (int n = 0; n < 4; ++n) {
            f32x4 z = {0.f, 0.f, 0.f, 0.f};
            acc[m][n] = z;
        }

    // prologue: stage tile 0 fully into buf0
    STAGE(A, bm0, 0, 0, 0, 0);
    STAGE(B, bn0, 0, 1, 0, 0);
    STAGE(A, bm0, 0, 0, 1, 0);
    STAGE(B, bn0, 0, 1, 1, 0);
    VM(0);
    BAR();

#pragma unroll 1
    for (int t = 0; t < NT - 1; ++t) {
        const int p = t & 1, q = p ^ 1;
        const int kn = (t + 1) * BK;
        bf16x8 a[4], b[4];
        // issue ALL stages for tile t+1 into buf q (q proven free by the
        // barrier we just passed); they have the whole tile to land.
        STAGE(A, bm0, q, 0, 0, kn);
        STAGE(B, bn0, q, 1, 0, kn);
        STAGE(A, bm0, q, 0, 1, kn);
        STAGE(B, bn0, q, 1, 1, kn);
        // kh0
        LOADB(p, 0);
        LOADA(p, 0, 0);
        LGKM0();
        MFMAQ(0);
        LOADA(p, 0, 1);
        LGKM0();
        MFMAQ(1);
        // kh1
        LOADB(p, 1);
        LOADA(p, 1, 0);
        LGKM0();
        MFMAQ(0);
        LOADA(p, 1, 1);
        LGKM0();
        MFMAQ(1);
        // single collectivized sync: stages (issued ~4 phases ago) are home
        VM(0);
        BAR();
    }
    // last tile t = NT-1 (p=1), no staging, no trailing sync needed
    {
        const int p = (NT - 1) & 1;
        bf16x8 a[4], b[4];
        LOADB(p, 0);
        LOADA(p, 0, 0);
        LGKM0();
        MFMAQ(0);
        LOADA(p, 0, 1);
        LGKM0();
        MFMAQ(1);
        LOADB(p, 1);
        LOADA(p, 1, 0);
        LGKM0();
        MFMAQ(0);
        LOADA(p, 1, 1);
        LGKM0();
        MFMAQ(1);
    }

    // epilogue: D layout col=lane&15, row=(lane>>4)*4+r  [m89/m91]
    const int r0 = ls * 4;
#pragma unroll
    for (int m = 0; m < 8; ++m)
#pragma unroll
        for (int n = 0; n < 4; ++n)
#pragma unroll
            for (int r = 0; r < 4; ++r) {
                int row = bm0 + wr * 128 + m * 16 + r0 + r;
                int col = bn0 + wc * 64 + n * 16 + lr;
                C[(size_t)row * ND + col] = acc[m][n][r];
            }
}

extern "C" void kernel_launch(void* const* d_in, const int* in_sizes, int n_in,
                              void* d_out, int out_size, void* d_ws, size_t ws_size,
                              hipStream_t stream) {
    const float* x     = (const float*)d_in[0];
    const int*   Wq    = (const int*)d_in[1];
    const float* scale = (const float*)d_in[2];
    const float* zero  = (const float*)d_in[3];
    float* out = (float*)d_out;

    uint16_t* Wb = (uint16_t*)d_ws;                                     // 32 MB
    uint16_t* xb = (uint16_t*)((char*)d_ws + (size_t)32 * 1024 * 1024); // 32 MB

    hipLaunchKernelGGL(prep_kernel, dim3(12288), dim3(256), 0, stream,
                       Wq, scale, zero, x, Wb, xb);
    hipLaunchKernelGGL(gemm_kernel, dim3(256), dim3(512), 0, stream, xb, Wb, out);
}

// Round 7
// 149.648 us; speedup vs baseline: 1.0208x; 1.0208x over previous
//
#include <hip/hip_runtime.h>
#include <stdint.h>

#define MD 4096
#define ND 4096
#define KD 4096
#define BK 64
#define NT (KD / BK)   // 64 K-tiles

typedef __bf16 bf16x8 __attribute__((ext_vector_type(8)));
typedef float f32x4 __attribute__((ext_vector_type(4)));

__device__ __forceinline__ uint32_t f32_to_bf16(float f) {
    union { float f; uint32_t u; } v; v.f = f;
    return (v.u + 0x7FFFu + ((v.u >> 16) & 1u)) >> 16;
}

#define GLDS16(gp, lp) \
    __builtin_amdgcn_global_load_lds((const __attribute__((address_space(1))) void*)(gp), \
                                     (__attribute__((address_space(3))) void*)(lp), 16, 0, 0)

// ---------------------------------------------------------------------------
// Fused prelude: blocks [0,4096) dequant W_q (int32-widened packed bytes) to
// bf16 Wb[4096][4096]; blocks [4096,12288) convert x fp32->bf16.
// ---------------------------------------------------------------------------
__global__ void prep_kernel(const int* __restrict__ Wq,
                            const float* __restrict__ scale,
                            const float* __restrict__ zero,
                            const float* __restrict__ x,
                            uint16_t* __restrict__ Wb,
                            uint16_t* __restrict__ xb) {
    int blk = blockIdx.x;
    if (blk < 4096) {
        int t = blk * 256 + threadIdx.x;
        int o  = t >> 9;
        int i0 = (t & 511) << 3;
        const uint4* wp = (const uint4*)Wq;
        uint4 pa = wp[t * 2], pb = wp[t * 2 + 1];
        uint32_t v[8] = {pa.x, pa.y, pa.z, pa.w, pb.x, pb.y, pb.z, pb.w};
        int gh = (o << 6) + (i0 >> 6);
        int gl = gh + (2048 << 6);
        float sh = scale[gh], zh = zero[gh];
        float sl = scale[gl], zl = zero[gl];
        uint32_t hw[4], lw[4];
#pragma unroll
        for (int p = 0; p < 4; ++p) {
            uint32_t b0 = v[p * 2], b1 = v[p * 2 + 1];
            uint32_t h0 = f32_to_bf16(((float)((b0 >> 4) & 15u) - zh) * sh);
            uint32_t h1 = f32_to_bf16(((float)((b1 >> 4) & 15u) - zh) * sh);
            uint32_t l0 = f32_to_bf16(((float)(b0 & 15u) - zl) * sl);
            uint32_t l1 = f32_to_bf16(((float)(b1 & 15u) - zl) * sl);
            hw[p] = h0 | (h1 << 16);
            lw[p] = l0 | (l1 << 16);
        }
        uint4 hv = {hw[0], hw[1], hw[2], hw[3]};
        uint4 lv = {lw[0], lw[1], lw[2], lw[3]};
        *(uint4*)&Wb[(size_t)o * KD + i0]          = hv;
        *(uint4*)&Wb[(size_t)(o + 2048) * KD + i0] = lv;
    } else {
        int t = (blk - 4096) * 256 + threadIdx.x;
        const float4* xp = (const float4*)x;
        float4 a = xp[t * 2], b = xp[t * 2 + 1];
        uint4 o;
        o.x = f32_to_bf16(a.x) | (f32_to_bf16(a.y) << 16);
        o.y = f32_to_bf16(a.z) | (f32_to_bf16(a.w) << 16);
        o.z = f32_to_bf16(b.x) | (f32_to_bf16(b.y) << 16);
        o.w = f32_to_bf16(b.z) | (f32_to_bf16(b.w) << 16);
        ((uint4*)xb)[t] = o;
    }
}

// ---------------------------------------------------------------------------
// m201-faithful 8-phase GEMM: 256x256 tile, BK=64, 8 waves (2Mx4N, 128x64).
// Phase = C-quadrant (2m x 4n) x K=64 = 16 MFMA. ph1 reads all B into regs.
// Per phase: stage ONE half-tile; 2 barriers; vmcnt(6) only at ph4.
// Main loop covers tiles 0..NT-2; tail = tile NT-1.  (R6 bug: loop stopped
// at NT-2 exclusive, skipping tile 62 -> absmax 40. Fixed bounds only.)
// Stage order @tile t: ph1 A-high(t+1)->free buf; ph2 B0(t+2), ph3 B1(t+2),
// ph4 A-low(t+2) -> LIVE buf (regions provably consumed: B by end ph1,
// A-low by end ph2; per-phase barriers order all reads before stage issue).
// LDS layout [buf][mat][256][64] bf16, XOR swizzle: 16B-slot ^= row&7.
// gload_lds dest is linear; swizzle applied on the GLOBAL source (rule #21).
// ---------------------------------------------------------------------------
#define BAR()  asm volatile("s_barrier" ::: "memory")
#define LGKM0() do { asm volatile("s_waitcnt lgkmcnt(0)" ::: "memory"); \
                     __builtin_amdgcn_sched_barrier(0); } while (0)
#define VM(N)  asm volatile("s_waitcnt vmcnt(" #N ")" ::: "memory")

__global__ __launch_bounds__(512, 2)
void gemm_kernel(const uint16_t* __restrict__ A,
                 const uint16_t* __restrict__ B,
                 float* __restrict__ C) {
    __shared__ uint16_t lds[65536];   // 128 KiB: [2 buf][2 mat][256][64]

    const int tid  = threadIdx.x;
    const int wave = tid >> 6;
    const int lane = tid & 63;
    const int wr = wave >> 2;                  // 0..1
    const int wc = wave & 3;                   // 0..3
    const int lr = lane & 15;
    const int ls = lane >> 4;
    const int xork = lr & 7;
    const int sl0 = ((0 * 4 + ls) ^ xork) * 8;   // kstep0 swizzled slot (elems)
    const int sl1 = ((1 * 4 + ls) ^ xork) * 8;   // kstep1
    const int sg  = (tid & 7) ^ ((tid >> 3) & 7); // pre-swizzled global slot
    const int grow = tid >> 3;                    // 0..63 staging row
    const int aoff = (wr * 128 + lr) * 64;
    const int boff = (wc * 64 + lr) * 64;

    // XCD-aware swizzle: 256 wgs, 8 XCDs, 32 contiguous tiles per XCD
    int bid = blockIdx.x;
    int wg = (bid & 7) * 32 + (bid >> 3);
    const int bm0 = (wg >> 4) * 256;
    const int bn0 = (wg & 15) * 256;

    const uint16_t* Ag = A + (size_t)bm0 * KD;
    const uint16_t* Bg = B + (size_t)bn0 * KD;

    f32x4 acc[8][4];
#pragma unroll
    for (int m = 0; m < 8; ++m)
#pragma unroll
        for (int n = 0; n < 4; ++n) {
            f32x4 z = {0.f, 0.f, 0.f, 0.f};
            acc[m][n] = z;
        }

// stage one 64-row slab: global rows GR0+grow (pre-swizzled col), LDS linear
#define ST1(GP, GR0, RB, LR0, KB) \
    GLDS16((GP) + (size_t)((GR0) + grow) * KD + (KB) + sg * 8, \
           lds + (RB) + (LR0) * 64 + wave * 512)

#define ST_B0(T)  do{ int kb=(T)*BK; int rb=((T)&1)*32768+16384; \
    ST1(Bg,   0, rb,   0, kb); ST1(Bg,  64, rb,  64, kb);}while(0)
#define ST_B1(T)  do{ int kb=(T)*BK; int rb=((T)&1)*32768+16384; \
    ST1(Bg, 128, rb, 128, kb); ST1(Bg, 192, rb, 192, kb);}while(0)
#define ST_ALO(T) do{ int kb=(T)*BK; int rb=((T)&1)*32768; \
    ST1(Ag,   0, rb,   0, kb); ST1(Ag, 128, rb, 128, kb);}while(0)
#define ST_AHI(T) do{ int kb=(T)*BK; int rb=((T)&1)*32768; \
    ST1(Ag,  64, rb,  64, kb); ST1(Ag, 192, rb, 192, kb);}while(0)

#define RD_A(P, Q) do{ const uint16_t* _a = lds + (P)*32768 + aoff + (Q)*2048; \
    a[0][0]=*(const bf16x8*)&_a[sl0];      a[0][1]=*(const bf16x8*)&_a[sl1]; \
    a[1][0]=*(const bf16x8*)&_a[1024+sl0]; a[1][1]=*(const bf16x8*)&_a[1024+sl1];}while(0)

#define RD_B(P) do{ const uint16_t* _b = lds + (P)*32768 + 16384 + boff; \
    _Pragma("unroll") \
    for (int n = 0; n < 4; ++n) { \
        b[n][0]=*(const bf16x8*)&_b[n*1024+sl0]; \
        b[n][1]=*(const bf16x8*)&_b[n*1024+sl1]; }}while(0)

#define MF16(Q) do{ __builtin_amdgcn_s_setprio(1); \
    _Pragma("unroll") \
    for (int ks = 0; ks < 2; ++ks) \
    _Pragma("unroll") \
    for (int mi = 0; mi < 2; ++mi) \
    _Pragma("unroll") \
    for (int n = 0; n < 4; ++n) \
        acc[(Q)*2+mi][n] = __builtin_amdgcn_mfma_f32_16x16x32_bf16( \
            a[mi][ks], b[n][ks], acc[(Q)*2+mi][n], 0, 0, 0); \
    __builtin_amdgcn_s_setprio(0);}while(0)

    bf16x8 a[2][2], b[4][2];

    // prologue (template): 4 halves of t0, VM(4); 3 halves of t1, VM(6); BAR
    ST_B0(0); ST_B1(0); ST_ALO(0); ST_AHI(0);
    VM(4);
    ST_B0(1); ST_B1(1); ST_ALO(1);
    VM(6);
    BAR();

#pragma unroll 1
    for (int t = 0; t < NT - 1; ++t) {          // tiles 0..62 (tail = 63)
        const int p = t & 1;
        // ph1: quad0 + all B; stage A-high(t+1) -> free buf
        RD_A(p, 0); RD_B(p); ST_AHI(t + 1);
        BAR(); LGKM0(); MF16(0); BAR();
        // ph2: quad1; stage B0(t+2) -> live buf (B consumed end ph1)
        RD_A(p, 1); if (t < NT - 2) ST_B0(t + 2);
        BAR(); LGKM0(); MF16(1); BAR();
        // ph3: quad2; stage B1(t+2)
        RD_A(p, 2); if (t < NT - 2) ST_B1(t + 2);
        BAR(); LGKM0(); MF16(2); BAR();
        // ph4: quad3; stage A-low(t+2); counted drain -> tile t+1 home
        RD_A(p, 3); if (t < NT - 2) ST_ALO(t + 2);
        BAR(); LGKM0(); MF16(3);
        if (t < NT - 2) { VM(6); } else { VM(0); }
        BAR();
    }
    // tail tile t = NT-1 (p=1): no staging
    {
        RD_A(1, 0); RD_B(1);
        BAR(); LGKM0(); MF16(0); BAR();
        RD_A(1, 1);
        BAR(); LGKM0(); MF16(1); BAR();
        RD_A(1, 2);
        BAR(); LGKM0(); MF16(2); BAR();
        RD_A(1, 3);
        LGKM0(); MF16(3);
    }

    // epilogue: D layout col=lane&15, row=(lane>>4)*4+r  [m89/m91]
    const int r0 = ls * 4;
#pragma unroll
    for (int m = 0; m < 8; ++m)
#pragma unroll
        for (int n = 0; n < 4; ++n)
#pragma unroll
            for (int r = 0; r < 4; ++r) {
                int row = bm0 + wr * 128 + m * 16 + r0 + r;
                int col = bn0 + wc * 64 + n * 16 + lr;
                C[(size_t)row * ND + col] = acc[m][n][r];
            }
}

extern "C" void kernel_launch(void* const* d_in, const int* in_sizes, int n_in,
                              void* d_out, int out_size, void* d_ws, size_t ws_size,
                              hipStream_t stream) {
    const float* x     = (const float*)d_in[0];
    const int*   Wq    = (const int*)d_in[1];
    const float* scale = (const float*)d_in[2];
    const float* zero  = (const float*)d_in[3];
    float* out = (float*)d_out;

    uint16_t* Wb = (uint16_t*)d_ws;                                     // 32 MB
    uint16_t* xb = (uint16_t*)((char*)d_ws + (size_t)32 * 1024 * 1024); // 32 MB

    hipLaunchKernelGGL(prep_kernel, dim3(12288), dim3(256), 0, stream,
                       Wq, scale, zero, x, Wb, xb);
    hipLaunchKernelGGL(gemm_kernel, dim3(256), dim3(512), 0, stream, xb, Wb, out);
}

// Round 8
// 147.971 us; speedup vs baseline: 1.0323x; 1.0113x over previous
//
#include <hip/hip_runtime.h>
#include <stdint.h>

#define MD 4096
#define ND 4096
#define KD 4096
#define BK 64
#define NT (KD / BK)   // 64 K-tiles

typedef __bf16 bf16x8 __attribute__((ext_vector_type(8)));
typedef float f32x4 __attribute__((ext_vector_type(4)));

__device__ __forceinline__ uint32_t f32_to_bf16(float f) {
    union { float f; uint32_t u; } v; v.f = f;
    return (v.u + 0x7FFFu + ((v.u >> 16) & 1u)) >> 16;
}

#define GLDS16(gp, lp) \
    __builtin_amdgcn_global_load_lds((const __attribute__((address_space(1))) void*)(gp), \
                                     (__attribute__((address_space(3))) void*)(lp), 16, 0, 0)

// ---------------------------------------------------------------------------
// Fused prelude: blocks [0,4096) dequant W_q (int32-widened packed bytes) to
// bf16 Wb[4096][4096]; blocks [4096,12288) convert x fp32->bf16.
// ---------------------------------------------------------------------------
__global__ void prep_kernel(const int* __restrict__ Wq,
                            const float* __restrict__ scale,
                            const float* __restrict__ zero,
                            const float* __restrict__ x,
                            uint16_t* __restrict__ Wb,
                            uint16_t* __restrict__ xb) {
    int blk = blockIdx.x;
    if (blk < 4096) {
        int t = blk * 256 + threadIdx.x;
        int o  = t >> 9;
        int i0 = (t & 511) << 3;
        const uint4* wp = (const uint4*)Wq;
        uint4 pa = wp[t * 2], pb = wp[t * 2 + 1];
        uint32_t v[8] = {pa.x, pa.y, pa.z, pa.w, pb.x, pb.y, pb.z, pb.w};
        int gh = (o << 6) + (i0 >> 6);
        int gl = gh + (2048 << 6);
        float sh = scale[gh], zh = zero[gh];
        float sl = scale[gl], zl = zero[gl];
        uint32_t hw[4], lw[4];
#pragma unroll
        for (int p = 0; p < 4; ++p) {
            uint32_t b0 = v[p * 2], b1 = v[p * 2 + 1];
            uint32_t h0 = f32_to_bf16(((float)((b0 >> 4) & 15u) - zh) * sh);
            uint32_t h1 = f32_to_bf16(((float)((b1 >> 4) & 15u) - zh) * sh);
            uint32_t l0 = f32_to_bf16(((float)(b0 & 15u) - zl) * sl);
            uint32_t l1 = f32_to_bf16(((float)(b1 & 15u) - zl) * sl);
            hw[p] = h0 | (h1 << 16);
            lw[p] = l0 | (l1 << 16);
        }
        uint4 hv = {hw[0], hw[1], hw[2], hw[3]};
        uint4 lv = {lw[0], lw[1], lw[2], lw[3]};
        *(uint4*)&Wb[(size_t)o * KD + i0]          = hv;
        *(uint4*)&Wb[(size_t)(o + 2048) * KD + i0] = lv;
    } else {
        int t = (blk - 4096) * 256 + threadIdx.x;
        const float4* xp = (const float4*)x;
        float4 a = xp[t * 2], b = xp[t * 2 + 1];
        uint4 o;
        o.x = f32_to_bf16(a.x) | (f32_to_bf16(a.y) << 16);
        o.y = f32_to_bf16(a.z) | (f32_to_bf16(a.w) << 16);
        o.z = f32_to_bf16(b.x) | (f32_to_bf16(b.y) << 16);
        o.w = f32_to_bf16(b.z) | (f32_to_bf16(b.w) << 16);
        ((uint4*)xb)[t] = o;
    }
}

// ---------------------------------------------------------------------------
// 256x256 tile, BK=64, 8 waves (2Mx4N, each 128x64). R3-prop fences (2
// barriers/tile, stages only into opposite buffer, VM(4) counted drains) +
// register-pipelined ds_reads: two A-frag sets (aX/aY), two B sets (bA/bB);
// next reads issued BEFORE the current MFMA cluster, counted lgkmcnt(8/4)
// waits (DS retires in order). Only 1 exposed lgkm stall per tile (entry).
// Mid VM(4);BAR moved right after the first MFMA quad so MFQ(kh0,c1) covers
// the kh1 read latency. LDS region(buf,mat,kh)=256x32 bf16; 8 regions=128KiB.
// ---------------------------------------------------------------------------
#define BAR()  asm volatile("s_barrier" ::: "memory")
#define LGKM(N) do { asm volatile("s_waitcnt lgkmcnt(" #N ")" ::: "memory"); \
                     __builtin_amdgcn_sched_barrier(0); } while (0)
#define VM(N)  asm volatile("s_waitcnt vmcnt(" #N ")" ::: "memory")

#define STAGE(PTR, GROW0, BUF, MAT, KH, KBASE) do {                                   \
    const uint16_t* _g = (PTR) + (size_t)((GROW0) + (tid >> 2)) * KD                  \
                         + (KBASE) + (KH) * 32 + sslot * 8;                           \
    uint16_t* _d = lds + (((BUF) * 2 + (MAT)) * 2 + (KH)) * 8192 + wave * 512;        \
    GLDS16(_g, _d);                                                                   \
    GLDS16(_g + 128 * KD, _d + 4096);                                                 \
} while (0)

#define RD_A(DST, P, KH, CH) do {                                                     \
    const uint16_t* _Ar = lds + (((P) * 2 + 0) * 2 + (KH)) * 8192;                    \
    _Pragma("unroll")                                                                 \
    for (int m = 0; m < 4; ++m)                                                       \
        DST[m] = *(const bf16x8*)&_Ar[(wr * 128 + ((CH) * 4 + m) * 16 + lr) * 32 + sx * 8]; \
} while (0)

#define RD_B(DST, P, KH) do {                                                         \
    const uint16_t* _Br = lds + (((P) * 2 + 1) * 2 + (KH)) * 8192;                    \
    _Pragma("unroll")                                                                 \
    for (int n = 0; n < 4; ++n)                                                       \
        DST[n] = *(const bf16x8*)&_Br[(wc * 64 + n * 16 + lr) * 32 + sx * 8];         \
} while (0)

#define MFQ(CH, AS, BS) do {                                                          \
    __builtin_amdgcn_s_setprio(1);                                                    \
    _Pragma("unroll")                                                                 \
    for (int m = 0; m < 4; ++m)                                                       \
    _Pragma("unroll")                                                                 \
    for (int n = 0; n < 4; ++n)                                                       \
        acc[(CH) * 4 + m][n] = __builtin_amdgcn_mfma_f32_16x16x32_bf16(               \
            AS[m], BS[n], acc[(CH) * 4 + m][n], 0, 0, 0);                             \
    __builtin_amdgcn_s_setprio(0);                                                    \
} while (0)

__global__ __launch_bounds__(512, 2)
void gemm_kernel(const uint16_t* __restrict__ A,
                 const uint16_t* __restrict__ B,
                 float* __restrict__ C) {
    __shared__ uint16_t lds[65536];   // 128 KiB

    const int tid  = threadIdx.x;
    const int wave = tid >> 6;
    const int lane = tid & 63;
    const int wr = wave >> 2;                  // 0..1
    const int wc = wave & 3;                   // 0..3
    const int lr = lane & 15;
    const int ls = lane >> 4;
    const int sx = ls ^ ((lr >> 1) & 3);              // swizzled read slot
    const int sslot = (tid & 3) ^ ((tid >> 3) & 3);   // pre-swizzled stage source slot

    // XCD-aware swizzle: 256 wgs, 8 XCDs, 32 contiguous tiles per XCD
    int bid = blockIdx.x;
    int wg = (bid & 7) * 32 + (bid >> 3);
    const int bm0 = (wg >> 4) * 256;
    const int bn0 = (wg & 15) * 256;

    f32x4 acc[8][4];
#pragma unroll
    for (int m = 0; m < 8; ++m)
#pragma unroll
        for (int n = 0; n < 4; ++n) {
            f32x4 z = {0.f, 0.f, 0.f, 0.f};
            acc[m][n] = z;
        }

    bf16x8 aX[4], aY[4], bA[4], bB[4];

    // prologue: stage tile 0 (kh0 then kh1) into buf0; drain kh0, kh1 flying
    STAGE(A, bm0, 0, 0, 0, 0);
    STAGE(B, bn0, 0, 1, 0, 0);
    STAGE(A, bm0, 0, 0, 1, 0);
    STAGE(B, bn0, 0, 1, 1, 0);
    VM(4);                      // kh0(0) home; kh1(0) [4 ops] in flight
    BAR();

#pragma unroll 1
    for (int t = 0; t < NT - 1; ++t) {          // tiles 0..62 (tail = 63)
        const int p = t & 1, q = p ^ 1;
        const int kn = (t + 1) * BK;
        // ---- kh0 half ----
        RD_B(bA, p, 0);                  // 4 ds
        RD_A(aX, p, 0, 0);               // 4 ds
        STAGE(A, bm0, q, 0, 0, kn);      // A-kh0(t+1) -> q
        LGKM(0);                         // entry stall (once per tile)
        RD_A(aY, p, 0, 1);               // next quad, lands under MFQ
        MFQ(0, aX, bA);
        STAGE(B, bn0, q, 1, 0, kn);      // B-kh0(t+1) -> q
        VM(4);                           // drain kh1(t) (issued tile t-1, deep)
        BAR();                           // kh1(t) visible to all
        // ---- kh1 half ----
        RD_B(bB, p, 1);                  // 4 ds (covered by MFQ below)
        RD_A(aX, p, 1, 0);               // 4 ds
        STAGE(A, bm0, q, 0, 1, kn);      // A-kh1(t+1) -> q
        LGKM(8);                         // aY home (was covered by MFQ(0))
        MFQ(1, aY, bA);                  // covers bB/aX latency
        RD_A(aY, p, 1, 1);               // 4 ds
        LGKM(4);                         // bB,aX home; aY flying
        MFQ(0, aX, bB);                  // covers aY latency
        STAGE(B, bn0, q, 1, 1, kn);      // B-kh1(t+1) -> q
        LGKM(0);                         // aY home (covered)
        MFQ(1, aY, bB);
        VM(4);                           // drain kh0(t+1) (issued this tile)
        BAR();
    }
    // tail tile t = NT-1 (p=1): no staging
    {
        const int p = (NT - 1) & 1;
        RD_B(bA, p, 0);
        RD_A(aX, p, 0, 0);
        LGKM(0);
        RD_A(aY, p, 0, 1);
        MFQ(0, aX, bA);
        VM(0);                           // drain kh1(NT-1)
        BAR();
        RD_B(bB, p, 1);
        RD_A(aX, p, 1, 0);
        LGKM(8);
        MFQ(1, aY, bA);
        RD_A(aY, p, 1, 1);
        LGKM(4);
        MFQ(0, aX, bB);
        LGKM(0);
        MFQ(1, aY, bB);
    }

    // epilogue: D layout col=lane&15, row=(lane>>4)*4+r  [m89/m91]
    const int r0 = ls * 4;
#pragma unroll
    for (int m = 0; m < 8; ++m)
#pragma unroll
        for (int n = 0; n < 4; ++n)
#pragma unroll
            for (int r = 0; r < 4; ++r) {
                int row = bm0 + wr * 128 + m * 16 + r0 + r;
                int col = bn0 + wc * 64 + n * 16 + lr;
                C[(size_t)row * ND + col] = acc[m][n][r];
            }
}

extern "C" void kernel_launch(void* const* d_in, const int* in_sizes, int n_in,
                              void* d_out, int out_size, void* d_ws, size_t ws_size,
                              hipStream_t stream) {
    const float* x     = (const float*)d_in[0];
    const int*   Wq    = (const int*)d_in[1];
    const float* scale = (const float*)d_in[2];
    const float* zero  = (const float*)d_in[3];
    float* out = (float*)d_out;

    uint16_t* Wb = (uint16_t*)d_ws;                                     // 32 MB
    uint16_t* xb = (uint16_t*)((char*)d_ws + (size_t)32 * 1024 * 1024); // 32 MB

    hipLaunchKernelGGL(prep_kernel, dim3(12288), dim3(256), 0, stream,
                       Wq, scale, zero, x, Wb, xb);
    hipLaunchKernelGGL(gemm_kernel, dim3(256), dim3(512), 0, stream, xb, Wb, out);
}